// Round 11
// baseline (105.535 us; speedup 1.0000x reference)
//
#include <hip/hip_runtime.h>

#define N_NODES 100000
#define NP 100096            // NB*128 padded node count
#define N_EDGES 3200000
#define NB 782               // buckets of 128 nodes
#define NBP 1024             // padded bins for scan
#define NHR 500              // binning blocks / regions
#define EPB (N_EDGES / NHR)  // 6400 edges per region (exact, mult of 4)
#define RS 8960              // region stride (words): 6400 + 3*782 pad <= 8746
#define BSB 512              // binning block threads
#define SPLIT 4              // region-split factor for consumer passes
#define RPB (NHR / SPLIT)    // 125 regions per consumer block
#define BSC 256              // consumer block threads: 16 groups x 16 lanes
#define NG 16                // groups per consumer block
#define NWG (NB * SPLIT)     // 3128 consumer blocks = 8 * 391 (exact)
#define CHUNK (NWG / 8)      // 391 consecutive logical blocks per XCD
#define SENT 128u            // sentinel: idx=128 (pad slot), src=0

typedef unsigned char u8;

// XCD-chunked swizzle: physical blocks round-robin XCDs (phys%8); give XCD k
// a CONTIGUOUS range of logical ids so adjacent buckets share that XCD's L2.
__device__ __forceinline__ void decode_bs(unsigned phys, int& b, int& sp) {
    unsigned L = (phys & 7u) * CHUNK + (phys >> 3);
    sp = (int)(L / NB);
    b  = (int)(L - (unsigned)sp * NB);
}

// ---------- binning: per-block LDS counting sort, padded runs, linear flush ----
// binned region-major: region r owns binned[r*RS ..). Bucket runs start at
// 4-word-aligned offsets; pads hold SENT. packed = (src<<8)|(dst&127).
// binned_b = low byte. runinfoT[b*NHR + r] = off | (nq<<16), nq = quads.
__global__ __launch_bounds__(BSB) void k_bin3(const int* __restrict__ src,
                                              const int* __restrict__ dst,
                                              unsigned* __restrict__ binned,
                                              u8* __restrict__ binned_b,
                                              unsigned* __restrict__ runinfoT) {
    __shared__ int hist[NBP];
    __shared__ int scanv[NBP];
    __shared__ int sh[BSB];
    __shared__ alignas(16) unsigned stage[RS];
    int t = threadIdx.x, blk = blockIdx.x;
    for (int i = t; i < NBP; i += BSB) hist[i] = 0;
    for (int i = t; i < RS; i += BSB) stage[i] = SENT;
    __syncthreads();
    int base = blk * EPB;
    for (int i = t * 4; i < EPB; i += BSB * 4) {
        int4 d = *(const int4*)(dst + base + i);
        atomicAdd(&hist[d.x >> 7], 1);
        atomicAdd(&hist[d.y >> 7], 1);
        atomicAdd(&hist[d.z >> 7], 1);
        atomicAdd(&hist[d.w >> 7], 1);
    }
    __syncthreads();
    // pad counts to mult of 4; exclusive scan (each thread owns 2 bins)
    int c0 = hist[2 * t], c1 = hist[2 * t + 1];
    int p0 = (c0 + 3) & ~3, p1 = (c1 + 3) & ~3;
    int v = p0 + p1;
    sh[t] = v;
    __syncthreads();
    for (int off = 1; off < BSB; off <<= 1) {
        int u = (t >= off) ? sh[t - off] : 0;
        __syncthreads();
        sh[t] += u;
        __syncthreads();
    }
    int excl = sh[t] - v;
    scanv[2 * t] = excl;
    scanv[2 * t + 1] = excl + p0;
    __syncthreads();
    for (int b = t; b < NB; b += BSB)
        runinfoT[(size_t)b * NHR + blk] =
            (unsigned)scanv[b] | ((unsigned)((hist[b] + 3) >> 2) << 16);
    __syncthreads();
    // scatter into stage; scanv doubles as cursor
    for (int i = t * 4; i < EPB; i += BSB * 4) {
        int4 s4 = *(const int4*)(src + base + i);
        int4 d4 = *(const int4*)(dst + base + i);
        int p;
        p = atomicAdd(&scanv[d4.x >> 7], 1);
        stage[p] = ((unsigned)s4.x << 8) | (unsigned)(d4.x & 127);
        p = atomicAdd(&scanv[d4.y >> 7], 1);
        stage[p] = ((unsigned)s4.y << 8) | (unsigned)(d4.y & 127);
        p = atomicAdd(&scanv[d4.z >> 7], 1);
        stage[p] = ((unsigned)s4.z << 8) | (unsigned)(d4.z & 127);
        p = atomicAdd(&scanv[d4.w >> 7], 1);
        stage[p] = ((unsigned)s4.w << 8) | (unsigned)(d4.w & 127);
    }
    __syncthreads();
    for (int i = t * 4; i < RS; i += BSB * 4) {
        *(int4*)(binned + (size_t)blk * RS + i) = *(const int4*)(stage + i);
        uchar4 w = make_uchar4((u8)(stage[i] & 255), (u8)(stage[i + 1] & 255),
                               (u8)(stage[i + 2] & 255), (u8)(stage[i + 3] & 255));
        *(uchar4*)(binned_b + (size_t)blk * RS + i) = w;
    }
}

// ---------- pass 1: partial degree (16-lane cooperative, byte quads) ----------
__global__ __launch_bounds__(BSC) void k_degP(const u8* __restrict__ binned_b,
                                              const unsigned* __restrict__ runinfoT,
                                              int* __restrict__ degP) {
    __shared__ int cnt[4][136];
    __shared__ unsigned rinfo[RPB];
    int t = threadIdx.x;
    int b, sp;
    decode_bs(blockIdx.x, b, sp);
    for (int i = t; i < 4 * 136; i += BSC) ((int*)cnt)[i] = 0;
    if (t < RPB) rinfo[t] = runinfoT[(size_t)b * NHR + sp * RPB + t];
    __syncthreads();
    int g = t >> 4, lane = t & 15, rep = g & 3;
    for (int rr = g; rr < RPB; rr += NG) {
        unsigned ri = rinfo[rr];
        int off = (int)(ri & 0xFFFFu), nq = (int)(ri >> 16);
        const uchar4* p =
            (const uchar4*)(binned_b + (size_t)(sp * RPB + rr) * RS + off);
        for (int j = lane; j < nq; j += 16) {
            uchar4 w = p[j];
            atomicAdd(&cnt[rep][w.x], 1);
            atomicAdd(&cnt[rep][w.y], 1);
            atomicAdd(&cnt[rep][w.z], 1);
            atomicAdd(&cnt[rep][w.w], 1);
        }
    }
    __syncthreads();
    if (t < 128)
        degP[(size_t)sp * NP + b * 128 + t] =
            cnt[0][t] + cnt[1][t] + cnt[2][t] + cnt[3][t];
}

// ---------- node pass 1: dinv, s ----------
__global__ __launch_bounds__(256) void k_node1(const int* __restrict__ degP,
                                               const float* __restrict__ x,
                                               float* __restrict__ dinv,
                                               float* __restrict__ s) {
    int v = blockIdx.x * 256 + threadIdx.x;
    if (v >= N_NODES) return;
    int d = 1 + degP[v] + degP[NP + v] + degP[2 * NP + v] + degP[3 * NP + v];
    float di = rsqrtf((float)d);
    dinv[v] = di;
    s[v] = di * x[v];
}

// ---------- pass 2: partial scatter1 (16-lane cooperative, word/lane) ----------
__global__ __launch_bounds__(BSC) void k_s1P(const unsigned* __restrict__ binned,
                                             const unsigned* __restrict__ runinfoT,
                                             const float* __restrict__ s,
                                             float* __restrict__ aggP) {
    __shared__ float acc[4][136];
    __shared__ unsigned rinfo[RPB];
    int t = threadIdx.x;
    int b, sp;
    decode_bs(blockIdx.x, b, sp);
    for (int i = t; i < 4 * 136; i += BSC) ((float*)acc)[i] = 0.f;
    if (t < RPB) rinfo[t] = runinfoT[(size_t)b * NHR + sp * RPB + t];
    __syncthreads();
    int g = t >> 4, lane = t & 15, rep = g & 3;
    for (int rr = g; rr < RPB; rr += NG) {
        unsigned ri = rinfo[rr];
        int off = (int)(ri & 0xFFFFu), nw = (int)(ri >> 16) * 4;
        const unsigned* p = binned + (size_t)(sp * RPB + rr) * RS + off;
        for (int j = lane; j < nw; j += 16) {
            unsigned w = p[j];
            float v = s[w >> 8];
            atomicAdd(&acc[rep][w & 255], v);
        }
    }
    __syncthreads();
    if (t < 128)
        aggP[(size_t)sp * NP + b * 128 + t] =
            acc[0][t] + acc[1][t] + acc[2][t] + acc[3][t];
}

// ---------- node pass 2: layer-1 MLP -> z ----------
__global__ __launch_bounds__(256) void k_node2(const float* __restrict__ aggP,
                                               const float* __restrict__ dinv,
                                               const float* __restrict__ s,
                                               const float* __restrict__ W1,
                                               const float* __restrict__ b1,
                                               const float* __restrict__ W2,
                                               float2* __restrict__ z) {
    int v = blockIdx.x * 256 + threadIdx.x;
    if (v >= N_NODES) return;
    float aggv = aggP[v] + aggP[NP + v] + aggP[2 * NP + v] + aggP[3 * NP + v];
    float di = dinv[v];
    float a = di * (aggv + s[v]);  // s[v] = self-loop term
    float z0 = 0.f, z1 = 0.f;
#pragma unroll
    for (int f = 0; f < 16; ++f) {
        float h = fmaxf(a * W1[f] + b1[f], 0.f);
        z0 += h * W2[2 * f + 0];
        z1 += h * W2[2 * f + 1];
    }
    z[v] = make_float2(di * z0, di * z1);
}

// ---------- pass 3: partial scatter2 (16-lane cooperative) ----------
__global__ __launch_bounds__(BSC) void k_s2P(const unsigned* __restrict__ binned,
                                             const unsigned* __restrict__ runinfoT,
                                             const float2* __restrict__ z,
                                             float2* __restrict__ agg2P) {
    __shared__ float accx[4][136], accy[4][136];
    __shared__ unsigned rinfo[RPB];
    int t = threadIdx.x;
    int b, sp;
    decode_bs(blockIdx.x, b, sp);
    for (int i = t; i < 4 * 136; i += BSC) {
        ((float*)accx)[i] = 0.f;
        ((float*)accy)[i] = 0.f;
    }
    if (t < RPB) rinfo[t] = runinfoT[(size_t)b * NHR + sp * RPB + t];
    __syncthreads();
    int g = t >> 4, lane = t & 15, rep = g & 3;
    for (int rr = g; rr < RPB; rr += NG) {
        unsigned ri = rinfo[rr];
        int off = (int)(ri & 0xFFFFu), nw = (int)(ri >> 16) * 4;
        const unsigned* p = binned + (size_t)(sp * RPB + rr) * RS + off;
        for (int j = lane; j < nw; j += 16) {
            unsigned w = p[j];
            float2 zz = z[w >> 8];
            atomicAdd(&accx[rep][w & 255], zz.x);
            atomicAdd(&accy[rep][w & 255], zz.y);
        }
    }
    __syncthreads();
    if (t < 128) {
        float ax = accx[0][t] + accx[1][t] + accx[2][t] + accx[3][t];
        float ay = accy[0][t] + accy[1][t] + accy[2][t] + accy[3][t];
        agg2P[(size_t)sp * NP + b * 128 + t] = make_float2(ax, ay);
    }
}

// ---------- node pass 3: epilogue -> out ----------
__global__ __launch_bounds__(256) void k_out(const float2* __restrict__ agg2P,
                                             const float* __restrict__ dinv,
                                             const float2* __restrict__ z,
                                             const float* __restrict__ b2,
                                             float2* __restrict__ out) {
    int v = blockIdx.x * 256 + threadIdx.x;
    if (v >= N_NODES) return;
    float2 a0 = agg2P[v], a1 = agg2P[NP + v];
    float2 a2 = agg2P[2 * NP + v], a3 = agg2P[3 * NP + v];
    float2 zz = z[v];
    float ax = a0.x + a1.x + a2.x + a3.x + zz.x;
    float ay = a0.y + a1.y + a2.y + a3.y + zz.y;
    float di = dinv[v];
    out[v] = make_float2(di * ax + b2[0], di * ay + b2[1]);
}

// ---------- fallback (device atomics), used only if ws too small ----------
__global__ void f_deg(const int* __restrict__ dst, int* __restrict__ deg) {
    int i = blockIdx.x * blockDim.x + threadIdx.x;
    if (i < N_EDGES) atomicAdd(&deg[dst[i]], 1);
}
__global__ void f_node1(const float* __restrict__ x, const int* __restrict__ deg,
                        float* __restrict__ dinv, float* __restrict__ s) {
    int v = blockIdx.x * blockDim.x + threadIdx.x;
    if (v < N_NODES) {
        float di = rsqrtf((float)(deg[v] + 1));
        dinv[v] = di;
        s[v] = di * x[v];
    }
}
__global__ void f_scatter1(const int* __restrict__ src, const int* __restrict__ dst,
                           const float* __restrict__ s, float* __restrict__ agg1) {
    int i = blockIdx.x * blockDim.x + threadIdx.x;
    if (i < N_EDGES) atomicAdd(&agg1[dst[i]], s[src[i]]);
}
__global__ void f_node2(const float* __restrict__ dinv, const float* __restrict__ s,
                        const float* __restrict__ agg1, const float* __restrict__ W1,
                        const float* __restrict__ b1, const float* __restrict__ W2,
                        float2* __restrict__ z) {
    int v = blockIdx.x * blockDim.x + threadIdx.x;
    if (v < N_NODES) {
        float di = dinv[v];
        float a = di * (agg1[v] + s[v]);
        float z0 = 0.f, z1 = 0.f;
#pragma unroll
        for (int f = 0; f < 16; ++f) {
            float h = fmaxf(a * W1[f] + b1[f], 0.f);
            z0 += h * W2[2 * f + 0];
            z1 += h * W2[2 * f + 1];
        }
        z[v] = make_float2(di * z0, di * z1);
    }
}
__global__ void f_scatter2(const int* __restrict__ src, const int* __restrict__ dst,
                           const float2* __restrict__ z, float* __restrict__ agg2) {
    int i = blockIdx.x * blockDim.x + threadIdx.x;
    if (i < N_EDGES) {
        float2 zz = z[src[i]];
        int d = dst[i];
        atomicAdd(&agg2[2 * d + 0], zz.x);
        atomicAdd(&agg2[2 * d + 1], zz.y);
    }
}
__global__ void f_out(const float* __restrict__ dinv, const float2* __restrict__ z,
                      const float2* __restrict__ agg2, const float* __restrict__ b2,
                      float2* __restrict__ out) {
    int v = blockIdx.x * blockDim.x + threadIdx.x;
    if (v < N_NODES) {
        float di = dinv[v];
        float2 a = agg2[v], zz = z[v];
        out[v] = make_float2(di * (a.x + zz.x) + b2[0], di * (a.y + zz.y) + b2[1]);
    }
}

// ---------- launch ----------
extern "C" void kernel_launch(void* const* d_in, const int* in_sizes, int n_in,
                              void* d_out, int out_size, void* d_ws, size_t ws_size,
                              hipStream_t stream) {
    const float* x  = (const float*)d_in[0];
    const int* eidx = (const int*)d_in[1];
    const float* W1 = (const float*)d_in[2];
    const float* b1 = (const float*)d_in[3];
    const float* W2 = (const float*)d_in[4];
    const float* b2 = (const float*)d_in[5];
    float* out = (float*)d_out;

    const int n = N_NODES;
    const int* src = eidx;
    const int* dst = eidx + N_EDGES;

    // workspace layout (32-bit words):
    // runinfoT[NB*NHR] | binned[NHR*RS] | binned_b[NHR*RS/4] | degP[4*NP] |
    // aggP[4*NP] | agg2P[8*NP] | dinv[NP] | s[NP] | z[2*NP]
    size_t oRun   = 0;
    size_t oBin   = oRun + (size_t)NB * NHR;
    size_t oBinB  = oBin + (size_t)NHR * RS;
    size_t oDegP  = oBinB + (size_t)NHR * RS / 4;
    size_t oAggP  = oDegP + (size_t)SPLIT * NP;
    size_t oAgg2P = oAggP + (size_t)SPLIT * NP;
    size_t oDinv  = oAgg2P + (size_t)2 * SPLIT * NP;
    size_t oS     = oDinv + NP;
    size_t oZ     = oS + NP;
    size_t need   = (oZ + 2 * NP) * sizeof(int);

    if (ws_size >= need) {
        int* wsI = (int*)d_ws;
        unsigned* runinfoT = (unsigned*)(wsI + oRun);
        unsigned* binned   = (unsigned*)(wsI + oBin);
        u8* binned_b       = (u8*)(wsI + oBinB);
        int*   degP  = wsI + oDegP;
        float* aggP  = (float*)(wsI + oAggP);
        float2* agg2P = (float2*)(wsI + oAgg2P);
        float* dinv = (float*)(wsI + oDinv);
        float* s    = (float*)(wsI + oS);
        float2* z   = (float2*)(wsI + oZ);

        k_bin3<<<NHR, BSB, 0, stream>>>(src, dst, binned, binned_b, runinfoT);
        k_degP<<<NWG, BSC, 0, stream>>>(binned_b, runinfoT, degP);
        k_node1<<<NP / 256, 256, 0, stream>>>(degP, x, dinv, s);
        k_s1P<<<NWG, BSC, 0, stream>>>(binned, runinfoT, s, aggP);
        k_node2<<<NP / 256, 256, 0, stream>>>(aggP, dinv, s, W1, b1, W2, z);
        k_s2P<<<NWG, BSC, 0, stream>>>(binned, runinfoT, z, agg2P);
        k_out<<<NP / 256, 256, 0, stream>>>(agg2P, dinv, z, b2, (float2*)out);
    } else {
        float* ws = (float*)d_ws;
        int* deg    = (int*)ws;
        float* agg1 = ws + n;
        float* agg2 = ws + 2 * n;
        float* dinv = ws + 4 * n;
        float* s    = ws + 5 * n;
        float* z    = ws + 6 * n;
        (void)hipMemsetAsync(d_ws, 0, (size_t)(4 * n) * sizeof(float), stream);
        const int gridE = (N_EDGES + 255) / 256;
        const int gridN = (n + 255) / 256;
        f_deg<<<gridE, 256, 0, stream>>>(dst, deg);
        f_node1<<<gridN, 256, 0, stream>>>(x, deg, dinv, s);
        f_scatter1<<<gridE, 256, 0, stream>>>(src, dst, s, agg1);
        f_node2<<<gridN, 256, 0, stream>>>(dinv, s, agg1, W1, b1, W2, (float2*)z);
        f_scatter2<<<gridE, 256, 0, stream>>>(src, dst, (const float2*)z, agg2);
        f_out<<<gridN, 256, 0, stream>>>(dinv, (const float2*)z, (const float2*)agg2,
                                         b2, (float2*)out);
    }
}

// Round 12
// 101.457 us; speedup vs baseline: 1.0402x; 1.0402x over previous
//
#include <hip/hip_runtime.h>

#define N_NODES 100000
#define NP 100096            // NB*128 padded node count
#define N_EDGES 3200000
#define NB 782               // buckets of 128 nodes
#define NBP 1024             // padded bins for scan
#define NHR 400              // binning blocks / regions
#define EPB (N_EDGES / NHR)  // 8000 edges per region (exact, mult of 4)
#define RS 10368             // region stride (words): 8000 + 3*782 = 10346 max
#define BSB 512              // binning block threads
#define SPLIT 8              // region-split factor for consumer passes
#define RPB (NHR / SPLIT)    // 50 regions per consumer block
#define BSC 256              // consumer block threads: 16 groups x 16 lanes
#define NG 16                // groups per consumer block
#define NWG (NB * SPLIT)     // 6256 consumer blocks = 8 * 782 (exact)
#define CHUNK (NWG / 8)      // 782 consecutive logical blocks per XCD
#define SENT 128u            // sentinel: low byte 128 (pad slot), src=0

typedef unsigned char u8;

// XCD-chunked swizzle: physical blocks round-robin XCDs (phys%8); give XCD k
// a CONTIGUOUS range of logical ids so adjacent buckets share that XCD's L2.
__device__ __forceinline__ void decode_bs(unsigned phys, int& b, int& sp) {
    unsigned L = (phys & 7u) * CHUNK + (phys >> 3);
    sp = (int)(L / NB);
    b  = (int)(L - (unsigned)sp * NB);
}

// ---------- binning: per-block LDS counting sort, padded runs, linear flush ----
__global__ __launch_bounds__(BSB) void k_bin3(const int* __restrict__ src,
                                              const int* __restrict__ dst,
                                              unsigned* __restrict__ binned,
                                              u8* __restrict__ binned_b,
                                              unsigned* __restrict__ runinfoT) {
    __shared__ int hist[NBP];
    __shared__ int scanv[NBP];
    __shared__ int sh[BSB];
    __shared__ alignas(16) unsigned stage[RS];
    int t = threadIdx.x, blk = blockIdx.x;
    for (int i = t; i < NBP; i += BSB) hist[i] = 0;
    for (int i = t; i < RS; i += BSB) stage[i] = SENT;
    __syncthreads();
    int base = blk * EPB;
    for (int i = t * 4; i < EPB; i += BSB * 4) {
        int4 d = *(const int4*)(dst + base + i);
        atomicAdd(&hist[d.x >> 7], 1);
        atomicAdd(&hist[d.y >> 7], 1);
        atomicAdd(&hist[d.z >> 7], 1);
        atomicAdd(&hist[d.w >> 7], 1);
    }
    __syncthreads();
    // pad counts to mult of 4; exclusive scan (each thread owns 2 bins)
    int c0 = hist[2 * t], c1 = hist[2 * t + 1];
    int p0 = (c0 + 3) & ~3, p1 = (c1 + 3) & ~3;
    int v = p0 + p1;
    sh[t] = v;
    __syncthreads();
    for (int off = 1; off < BSB; off <<= 1) {
        int u = (t >= off) ? sh[t - off] : 0;
        __syncthreads();
        sh[t] += u;
        __syncthreads();
    }
    int excl = sh[t] - v;
    scanv[2 * t] = excl;
    scanv[2 * t + 1] = excl + p0;
    __syncthreads();
    for (int b = t; b < NB; b += BSB)
        runinfoT[(size_t)b * NHR + blk] =
            (unsigned)scanv[b] | ((unsigned)((hist[b] + 3) >> 2) << 16);
    __syncthreads();
    // scatter into stage; scanv doubles as cursor
    for (int i = t * 4; i < EPB; i += BSB * 4) {
        int4 s4 = *(const int4*)(src + base + i);
        int4 d4 = *(const int4*)(dst + base + i);
        int p;
        p = atomicAdd(&scanv[d4.x >> 7], 1);
        stage[p] = ((unsigned)s4.x << 8) | (unsigned)(d4.x & 127);
        p = atomicAdd(&scanv[d4.y >> 7], 1);
        stage[p] = ((unsigned)s4.y << 8) | (unsigned)(d4.y & 127);
        p = atomicAdd(&scanv[d4.z >> 7], 1);
        stage[p] = ((unsigned)s4.z << 8) | (unsigned)(d4.z & 127);
        p = atomicAdd(&scanv[d4.w >> 7], 1);
        stage[p] = ((unsigned)s4.w << 8) | (unsigned)(d4.w & 127);
    }
    __syncthreads();
    for (int i = t * 4; i < RS; i += BSB * 4) {
        *(int4*)(binned + (size_t)blk * RS + i) = *(const int4*)(stage + i);
        uchar4 w = make_uchar4((u8)(stage[i] & 255), (u8)(stage[i + 1] & 255),
                               (u8)(stage[i + 2] & 255), (u8)(stage[i + 3] & 255));
        *(uchar4*)(binned_b + (size_t)blk * RS + i) = w;
    }
}

// ---------- pass 1: partial degree (16-lane cooperative, byte quads) ----------
__global__ __launch_bounds__(BSC) void k_degP(const u8* __restrict__ binned_b,
                                              const unsigned* __restrict__ runinfoT,
                                              int* __restrict__ degP) {
    __shared__ int cnt[8][136];
    __shared__ unsigned rinfo[RPB];
    int t = threadIdx.x;
    int b, sp;
    decode_bs(blockIdx.x, b, sp);
    for (int i = t; i < 8 * 136; i += BSC) ((int*)cnt)[i] = 0;
    if (t < RPB) rinfo[t] = runinfoT[(size_t)b * NHR + sp * RPB + t];
    __syncthreads();
    int g = t >> 4, lane = t & 15, rep = g & 7;
    for (int rr = g; rr < RPB; rr += NG) {
        unsigned ri = rinfo[rr];
        int off = (int)(ri & 0xFFFFu), nq = (int)(ri >> 16);
        const uchar4* p =
            (const uchar4*)(binned_b + (size_t)(sp * RPB + rr) * RS + off);
        for (int j = lane; j < nq; j += 16) {
            uchar4 w = p[j];
            if (w.x != 128) atomicAdd(&cnt[rep][w.x], 1);
            if (w.y != 128) atomicAdd(&cnt[rep][w.y], 1);
            if (w.z != 128) atomicAdd(&cnt[rep][w.z], 1);
            if (w.w != 128) atomicAdd(&cnt[rep][w.w], 1);
        }
    }
    __syncthreads();
    if (t < 128) {
        int d = 0;
#pragma unroll
        for (int c = 0; c < 8; ++c) d += cnt[c][t];
        degP[(size_t)sp * NP + b * 128 + t] = d;
    }
}

// ---------- node pass 1: dinv, s ----------
__global__ __launch_bounds__(256) void k_node1(const int* __restrict__ degP,
                                               const float* __restrict__ x,
                                               float* __restrict__ dinv,
                                               float* __restrict__ s) {
    int v = blockIdx.x * 256 + threadIdx.x;
    if (v >= N_NODES) return;
    int d = 1;
#pragma unroll
    for (int c = 0; c < SPLIT; ++c) d += degP[(size_t)c * NP + v];
    float di = rsqrtf((float)d);
    dinv[v] = di;
    s[v] = di * x[v];
}

// ---------- pass 2: partial scatter1 (16-lane cooperative, guard) ----------
__global__ __launch_bounds__(BSC) void k_s1P(const unsigned* __restrict__ binned,
                                             const unsigned* __restrict__ runinfoT,
                                             const float* __restrict__ s,
                                             float* __restrict__ aggP) {
    __shared__ float acc[8][136];
    __shared__ unsigned rinfo[RPB];
    int t = threadIdx.x;
    int b, sp;
    decode_bs(blockIdx.x, b, sp);
    for (int i = t; i < 8 * 136; i += BSC) ((float*)acc)[i] = 0.f;
    if (t < RPB) rinfo[t] = runinfoT[(size_t)b * NHR + sp * RPB + t];
    __syncthreads();
    int g = t >> 4, lane = t & 15, rep = g & 7;
    for (int rr = g; rr < RPB; rr += NG) {
        unsigned ri = rinfo[rr];
        int off = (int)(ri & 0xFFFFu), nw = (int)(ri >> 16) * 4;
        const unsigned* p = binned + (size_t)(sp * RPB + rr) * RS + off;
        for (int j = lane; j < nw; j += 16) {
            unsigned w = p[j];
            if ((w & 255u) != 128u) {
                float v = s[w >> 8];
                atomicAdd(&acc[rep][w & 255], v);
            }
        }
    }
    __syncthreads();
    if (t < 128) {
        float a = 0.f;
#pragma unroll
        for (int c = 0; c < 8; ++c) a += acc[c][t];
        aggP[(size_t)sp * NP + b * 128 + t] = a;
    }
}

// ---------- node pass 2: layer-1 MLP -> z ----------
__global__ __launch_bounds__(256) void k_node2(const float* __restrict__ aggP,
                                               const float* __restrict__ dinv,
                                               const float* __restrict__ s,
                                               const float* __restrict__ W1,
                                               const float* __restrict__ b1,
                                               const float* __restrict__ W2,
                                               float2* __restrict__ z) {
    int v = blockIdx.x * 256 + threadIdx.x;
    if (v >= N_NODES) return;
    float aggv = s[v];  // self-loop term
#pragma unroll
    for (int c = 0; c < SPLIT; ++c) aggv += aggP[(size_t)c * NP + v];
    float di = dinv[v];
    float a = di * aggv;
    float z0 = 0.f, z1 = 0.f;
#pragma unroll
    for (int f = 0; f < 16; ++f) {
        float h = fmaxf(a * W1[f] + b1[f], 0.f);
        z0 += h * W2[2 * f + 0];
        z1 += h * W2[2 * f + 1];
    }
    z[v] = make_float2(di * z0, di * z1);
}

// ---------- pass 3: partial scatter2 (16-lane cooperative, guard) ----------
__global__ __launch_bounds__(BSC) void k_s2P(const unsigned* __restrict__ binned,
                                             const unsigned* __restrict__ runinfoT,
                                             const float2* __restrict__ z,
                                             float2* __restrict__ agg2P) {
    __shared__ float accx[8][136], accy[8][136];
    __shared__ unsigned rinfo[RPB];
    int t = threadIdx.x;
    int b, sp;
    decode_bs(blockIdx.x, b, sp);
    for (int i = t; i < 8 * 136; i += BSC) {
        ((float*)accx)[i] = 0.f;
        ((float*)accy)[i] = 0.f;
    }
    if (t < RPB) rinfo[t] = runinfoT[(size_t)b * NHR + sp * RPB + t];
    __syncthreads();
    int g = t >> 4, lane = t & 15, rep = g & 7;
    for (int rr = g; rr < RPB; rr += NG) {
        unsigned ri = rinfo[rr];
        int off = (int)(ri & 0xFFFFu), nw = (int)(ri >> 16) * 4;
        const unsigned* p = binned + (size_t)(sp * RPB + rr) * RS + off;
        for (int j = lane; j < nw; j += 16) {
            unsigned w = p[j];
            if ((w & 255u) != 128u) {
                float2 zz = z[w >> 8];
                atomicAdd(&accx[rep][w & 255], zz.x);
                atomicAdd(&accy[rep][w & 255], zz.y);
            }
        }
    }
    __syncthreads();
    if (t < 128) {
        float ax = 0.f, ay = 0.f;
#pragma unroll
        for (int c = 0; c < 8; ++c) {
            ax += accx[c][t];
            ay += accy[c][t];
        }
        agg2P[(size_t)sp * NP + b * 128 + t] = make_float2(ax, ay);
    }
}

// ---------- node pass 3: epilogue -> out ----------
__global__ __launch_bounds__(256) void k_out(const float2* __restrict__ agg2P,
                                             const float* __restrict__ dinv,
                                             const float2* __restrict__ z,
                                             const float* __restrict__ b2,
                                             float2* __restrict__ out) {
    int v = blockIdx.x * 256 + threadIdx.x;
    if (v >= N_NODES) return;
    float2 zz = z[v];
    float ax = zz.x, ay = zz.y;
#pragma unroll
    for (int c = 0; c < SPLIT; ++c) {
        float2 a = agg2P[(size_t)c * NP + v];
        ax += a.x;
        ay += a.y;
    }
    float di = dinv[v];
    out[v] = make_float2(di * ax + b2[0], di * ay + b2[1]);
}

// ---------- fallback (device atomics), used only if ws too small ----------
__global__ void f_deg(const int* __restrict__ dst, int* __restrict__ deg) {
    int i = blockIdx.x * blockDim.x + threadIdx.x;
    if (i < N_EDGES) atomicAdd(&deg[dst[i]], 1);
}
__global__ void f_node1(const float* __restrict__ x, const int* __restrict__ deg,
                        float* __restrict__ dinv, float* __restrict__ s) {
    int v = blockIdx.x * blockDim.x + threadIdx.x;
    if (v < N_NODES) {
        float di = rsqrtf((float)(deg[v] + 1));
        dinv[v] = di;
        s[v] = di * x[v];
    }
}
__global__ void f_scatter1(const int* __restrict__ src, const int* __restrict__ dst,
                           const float* __restrict__ s, float* __restrict__ agg1) {
    int i = blockIdx.x * blockDim.x + threadIdx.x;
    if (i < N_EDGES) atomicAdd(&agg1[dst[i]], s[src[i]]);
}
__global__ void f_node2(const float* __restrict__ dinv, const float* __restrict__ s,
                        const float* __restrict__ agg1, const float* __restrict__ W1,
                        const float* __restrict__ b1, const float* __restrict__ W2,
                        float2* __restrict__ z) {
    int v = blockIdx.x * blockDim.x + threadIdx.x;
    if (v < N_NODES) {
        float di = dinv[v];
        float a = di * (agg1[v] + s[v]);
        float z0 = 0.f, z1 = 0.f;
#pragma unroll
        for (int f = 0; f < 16; ++f) {
            float h = fmaxf(a * W1[f] + b1[f], 0.f);
            z0 += h * W2[2 * f + 0];
            z1 += h * W2[2 * f + 1];
        }
        z[v] = make_float2(di * z0, di * z1);
    }
}
__global__ void f_scatter2(const int* __restrict__ src, const int* __restrict__ dst,
                           const float2* __restrict__ z, float* __restrict__ agg2) {
    int i = blockIdx.x * blockDim.x + threadIdx.x;
    if (i < N_EDGES) {
        float2 zz = z[src[i]];
        int d = dst[i];
        atomicAdd(&agg2[2 * d + 0], zz.x);
        atomicAdd(&agg2[2 * d + 1], zz.y);
    }
}
__global__ void f_out(const float* __restrict__ dinv, const float2* __restrict__ z,
                      const float2* __restrict__ agg2, const float* __restrict__ b2,
                      float2* __restrict__ out) {
    int v = blockIdx.x * blockDim.x + threadIdx.x;
    if (v < N_NODES) {
        float di = dinv[v];
        float2 a = agg2[v], zz = z[v];
        out[v] = make_float2(di * (a.x + zz.x) + b2[0], di * (a.y + zz.y) + b2[1]);
    }
}

// ---------- launch ----------
extern "C" void kernel_launch(void* const* d_in, const int* in_sizes, int n_in,
                              void* d_out, int out_size, void* d_ws, size_t ws_size,
                              hipStream_t stream) {
    const float* x  = (const float*)d_in[0];
    const int* eidx = (const int*)d_in[1];
    const float* W1 = (const float*)d_in[2];
    const float* b1 = (const float*)d_in[3];
    const float* W2 = (const float*)d_in[4];
    const float* b2 = (const float*)d_in[5];
    float* out = (float*)d_out;

    const int n = N_NODES;
    const int* src = eidx;
    const int* dst = eidx + N_EDGES;

    // workspace layout (32-bit words):
    // runinfoT[NB*NHR] | binned[NHR*RS] | binned_b[NHR*RS/4] | degP[8*NP] |
    // aggP[8*NP] | agg2P[16*NP] | dinv[NP] | s[NP] | z[2*NP]
    size_t oRun   = 0;
    size_t oBin   = oRun + (size_t)NB * NHR;
    size_t oBinB  = oBin + (size_t)NHR * RS;
    size_t oDegP  = oBinB + (size_t)NHR * RS / 4;
    size_t oAggP  = oDegP + (size_t)SPLIT * NP;
    size_t oAgg2P = oAggP + (size_t)SPLIT * NP;
    size_t oDinv  = oAgg2P + (size_t)2 * SPLIT * NP;
    size_t oS     = oDinv + NP;
    size_t oZ     = oS + NP;
    size_t need   = (oZ + 2 * NP) * sizeof(int);

    if (ws_size >= need) {
        int* wsI = (int*)d_ws;
        unsigned* runinfoT = (unsigned*)(wsI + oRun);
        unsigned* binned   = (unsigned*)(wsI + oBin);
        u8* binned_b       = (u8*)(wsI + oBinB);
        int*   degP  = wsI + oDegP;
        float* aggP  = (float*)(wsI + oAggP);
        float2* agg2P = (float2*)(wsI + oAgg2P);
        float* dinv = (float*)(wsI + oDinv);
        float* s    = (float*)(wsI + oS);
        float2* z   = (float2*)(wsI + oZ);

        k_bin3<<<NHR, BSB, 0, stream>>>(src, dst, binned, binned_b, runinfoT);
        k_degP<<<NWG, BSC, 0, stream>>>(binned_b, runinfoT, degP);
        k_node1<<<NP / 256, 256, 0, stream>>>(degP, x, dinv, s);
        k_s1P<<<NWG, BSC, 0, stream>>>(binned, runinfoT, s, aggP);
        k_node2<<<NP / 256, 256, 0, stream>>>(aggP, dinv, s, W1, b1, W2, z);
        k_s2P<<<NWG, BSC, 0, stream>>>(binned, runinfoT, z, agg2P);
        k_out<<<NP / 256, 256, 0, stream>>>(agg2P, dinv, z, b2, (float2*)out);
    } else {
        float* ws = (float*)d_ws;
        int* deg    = (int*)ws;
        float* agg1 = ws + n;
        float* agg2 = ws + 2 * n;
        float* dinv = ws + 4 * n;
        float* s    = ws + 5 * n;
        float* z    = ws + 6 * n;
        (void)hipMemsetAsync(d_ws, 0, (size_t)(4 * n) * sizeof(float), stream);
        const int gridE = (N_EDGES + 255) / 256;
        const int gridN = (n + 255) / 256;
        f_deg<<<gridE, 256, 0, stream>>>(dst, deg);
        f_node1<<<gridN, 256, 0, stream>>>(x, deg, dinv, s);
        f_scatter1<<<gridE, 256, 0, stream>>>(src, dst, s, agg1);
        f_node2<<<gridN, 256, 0, stream>>>(dinv, s, agg1, W1, b1, W2, (float2*)z);
        f_scatter2<<<gridE, 256, 0, stream>>>(src, dst, (const float2*)z, agg2);
        f_out<<<gridN, 256, 0, stream>>>(dinv, (const float2*)z, (const float2*)agg2,
                                         b2, (float2*)out);
    }
}